// Round 3
// baseline (42.302 us; speedup 1.0000x reference)
//
#include <hip/hip_runtime.h>
#include <math.h>

// ---------------------------------------------------------------------------
// FashionNetLoss: 3-scale YOLO-ish loss.
//  * obj focal loss is a mean over ALL cells, but target is 0 except at the
//    512 occupied cells per scale -> sum focal(x,0) over all cells, then a
//    per-target correction focal(x,t)-focal(x,0).
//  * box & cls losses only involve the 512 occupied cells per scale.
//  * npos == 512 per scale.
// ws layout (floats): [scale*4 + {0:focal_all, 1:box_sum, 2:cls_sum, 3:obj_corr}]
//                     ws[16] (as int) = block completion counter.
//
// R2 post-mortem: target gather still ~20us — latency-bound (24 waves for
// 27.6k scattered cachelines, 18-deep load chains at VGPR=32). R3: split the
// gather by channel (one thread per (target,scale,class) for the 13 cls
// terms), put gather blocks FIRST so streaming blocks hide their latency,
// and fuse finalize via completion counter (2 launches total).
// ---------------------------------------------------------------------------

#define NBLK_BOX 6     // 1536 threads: one per (target,scale), ch0..4 gather
#define NBLK_CLS 78    // 19968 threads: one per (target,scale,class)
#define NBLK_TGT (NBLK_BOX + NBLK_CLS)          // 84
#define NBLK_SWEEP 1050
#define NBLK_TOTAL (NBLK_TGT + NBLK_SWEEP)      // 1134

namespace {
__device__ __forceinline__ float bce_logits(float x, float t) {
    return fmaxf(x, 0.0f) - x * t + log1pf(expf(-fabsf(x)));
}
__device__ __forceinline__ float focal_term(float x, float t) {
    float b = bce_logits(x, t);
    float pt = expf(-b);
    float om = fmaxf(1.0f - pt, 0.0f);
    return 0.25f * om * sqrtf(om) * b;   // alpha=0.25, gamma=1.5
}
} // namespace

__global__ void fnl_zero_ws(float* __restrict__ ws) {
    if (threadIdx.x < 17) ws[threadIdx.x] = 0.0f;
}

__global__ void __launch_bounds__(256) fnl_main(
    const float* __restrict__ p0, const float* __restrict__ p1,
    const float* __restrict__ p2, const float* __restrict__ tg,
    float* __restrict__ ws, float* __restrict__ out) {
    __shared__ float sm[4];
    const float* const ps[3] = {p0, p1, p2};
    const int gss[3] = {160, 80, 40};

    if (blockIdx.x < NBLK_BOX) {
        // ---- box + obj-correction: one thread per (target,scale) ----------
        int gid = blockIdx.x * 256 + threadIdx.x;   // [0,1536)
        int s = gid >> 9;                            // wave-uniform
        int t = gid & 511;

        const float bi  = tg[t * 6 + 0];
        const float cx  = tg[t * 6 + 2];
        const float cy  = tg[t * 6 + 3];
        const float w   = tg[t * 6 + 4];
        const float h   = tg[t * 6 + 5];
        const int b = (int)bi;

        const int gs = gss[s];
        const float fgs = (float)gs;
        float cxs = cx * fgs, cys = cy * fgs;
        int gi = (int)floorf(cxs); gi = min(max(gi, 0), gs - 1);
        int gj = (int)floorf(cys); gj = min(max(gj, 0), gs - 1);
        const float tx = cxs - (float)gi;
        const float ty = cys - (float)gj;
        const float tw = w * fgs;
        const float th = h * fgs;

        const int hw = gs * gs;
        const float* base = ps[s] + (size_t)b * 18 * hw + (size_t)gj * gs + gi;
        float pr0 = base[0];
        float pr1 = base[(size_t)hw];
        float pr2 = base[(size_t)2 * hw];
        float pr3 = base[(size_t)3 * hw];
        float pr4 = base[(size_t)4 * hw];

        const float px = 1.0f / (1.0f + expf(-pr0));
        const float py = 1.0f / (1.0f + expf(-pr1));
        const float pw = pr2;
        const float ph = pr3;

        const float eps = 1e-7f;
        float px1 = px - pw * 0.5f, px2 = px + pw * 0.5f;
        float py1 = py - ph * 0.5f, py2 = py + ph * 0.5f;
        float tx1 = tx - tw * 0.5f, tx2 = tx + tw * 0.5f;
        float ty1 = ty - th * 0.5f, ty2 = ty + th * 0.5f;
        float iw = fmaxf(fminf(px2, tx2) - fmaxf(px1, tx1), 0.0f);
        float ih = fmaxf(fminf(py2, ty2) - fmaxf(py1, ty1), 0.0f);
        float inter = iw * ih;
        float uni = pw * ph + tw * th - inter + eps;
        float iou = inter / uni;
        float ew = fmaxf(fmaxf(px2, tx2) - fminf(px1, tx1), 0.0f);
        float eh = fmaxf(fmaxf(py2, ty2) - fminf(py1, ty1), 0.0f);
        float c2 = ew * ew + eh * eh + eps;
        float rho2 = (px - tx) * (px - tx) + (py - ty) * (py - ty);
        const float four_over_pi2 = 0.405284734569351085775517852f;
        float dat = atanf(tw / (th + eps)) - atanf(pw / (ph + eps));
        float v = four_over_pi2 * dat * dat;
        float alpha = v / (1.0f - iou + v + eps);
        float ciou = iou - (rho2 / c2 + v * alpha);

        float box = 1.0f - ciou;
        float tobj = fmaxf(ciou, 0.0f);
        float corr = focal_term(pr4, tobj) - focal_term(pr4, 0.0f);

        for (int off = 32; off; off >>= 1) {
            box  += __shfl_down(box, off);
            corr += __shfl_down(corr, off);
        }
        if ((threadIdx.x & 63) == 0) {
            atomicAdd(&ws[s * 4 + 1], box);
            atomicAdd(&ws[s * 4 + 3], corr);
        }
    } else if (blockIdx.x < NBLK_TGT) {
        // ---- cls: one thread per (target,scale,class) ---------------------
        int g = (blockIdx.x - NBLK_BOX) * 256 + threadIdx.x;  // [0,19968)
        int sk = g >> 9;          // wave-uniform: (s*13 + k)
        int t  = g & 511;
        int s  = sk / 13;
        int k  = sk - s * 13;

        const float bi  = tg[t * 6 + 0];
        const float clf = tg[t * 6 + 1];
        const float cx  = tg[t * 6 + 2];
        const float cy  = tg[t * 6 + 3];
        const int b = (int)bi;
        const int cls = (int)clf;

        const int gs = gss[s];
        const float fgs = (float)gs;
        int gi = (int)floorf(cx * fgs); gi = min(max(gi, 0), gs - 1);
        int gj = (int)floorf(cy * fgs); gj = min(max(gj, 0), gs - 1);

        const int hw = gs * gs;
        float x = ps[s][(size_t)b * 18 * hw + (size_t)(5 + k) * hw +
                        (size_t)gj * gs + gi];
        float tc = (k == cls) ? 0.95f : 0.0f;
        float c = bce_logits(x, tc);

        for (int off = 32; off; off >>= 1) c += __shfl_down(c, off);
        if ((threadIdx.x & 63) == 0) atomicAdd(&ws[s * 4 + 2], c);
    } else {
        // ---- focal(x,0) sweep over channel-4 planes (float4) --------------
        int i = (blockIdx.x - NBLK_TGT) * 256 + threadIdx.x;
        const float* p;
        int hw4, scale, idx;
        if (i < 204800)      { p = p0; hw4 = 6400; scale = 0; idx = i; }
        else if (i < 256000) { p = p1; hw4 = 1600; scale = 1; idx = i - 204800; }
        else                 { p = p2; hw4 = 400;  scale = 2; idx = i - 256000; }
        int b = idx / hw4;
        int pos4 = idx - b * hw4;
        int hw = hw4 * 4;
        const float4* src =
            reinterpret_cast<const float4*>(p + (size_t)b * 18 * hw + (size_t)4 * hw);
        float4 x = src[pos4];
        float v = focal_term(x.x, 0.0f) + focal_term(x.y, 0.0f) +
                  focal_term(x.z, 0.0f) + focal_term(x.w, 0.0f);

        for (int off = 32; off; off >>= 1) v += __shfl_down(v, off);
        if ((threadIdx.x & 63) == 0) sm[threadIdx.x >> 6] = v;
        __syncthreads();
        if (threadIdx.x == 0)
            atomicAdd(&ws[scale * 4 + 0], sm[0] + sm[1] + sm[2] + sm[3]);
    }

    // ---- last-block finalize (device-scope counter) -----------------------
    __syncthreads();
    if (threadIdx.x == 0) {
        __threadfence();
        int old = atomicAdd((int*)ws + 16, 1);
        if (old == NBLK_TOTAL - 1) {
            float acc[12];
            #pragma unroll
            for (int i = 0; i < 12; ++i) acc[i] = atomicAdd(&ws[i], 0.0f);
            const float cells[3] = {819200.0f, 204800.0f, 51200.0f};
            const float npos = 512.0f;
            float lb = 0.0f, lo = 0.0f, lc = 0.0f;
            for (int s = 0; s < 3; ++s) {
                lb += acc[s * 4 + 1] / npos;
                lo += (acc[s * 4 + 0] + acc[s * 4 + 3]) / cells[s];
                lc += acc[s * 4 + 2] / (npos * 13.0f);
            }
            out[0] = 5.0f * lb + 1.0f * lo + 0.5f * lc;
            out[1] = lb;
            out[2] = lo;
            out[3] = lc;
        }
    }
}

extern "C" void kernel_launch(void* const* d_in, const int* in_sizes, int n_in,
                              void* d_out, int out_size, void* d_ws, size_t ws_size,
                              hipStream_t stream) {
    const float* p0 = (const float*)d_in[0];
    const float* p1 = (const float*)d_in[1];
    const float* p2 = (const float*)d_in[2];
    const float* tg = (const float*)d_in[3];
    float* ws = (float*)d_ws;
    float* out = (float*)d_out;

    fnl_zero_ws<<<1, 64, 0, stream>>>(ws);
    fnl_main<<<NBLK_TOTAL, 256, 0, stream>>>(p0, p1, p2, tg, ws, out);
}

// Round 4
// 32.163 us; speedup vs baseline: 1.3152x; 1.3152x over previous
//
#include <hip/hip_runtime.h>
#include <math.h>

// ---------------------------------------------------------------------------
// FashionNetLoss: 3-scale YOLO-ish loss.
//  * obj focal loss is a mean over ALL cells, but target is 0 except at the
//    512 occupied cells per scale -> sum focal(x,0) over all cells, then a
//    per-target correction focal(x,t)-focal(x,0).
//  * box & cls losses only involve the 512 occupied cells per scale.
//  * npos == 512 per scale.
// ws layout (floats): [scale*4 + {0:focal_all, 1:box_sum, 2:cls_sum, 3:obj_corr}]
//
// R3 post-mortem: fusing finalize with __threadfence() (device scope) into
// every block cost ~10us — on gfx950 a device-scope fence implies L2
// writeback/invalidate maintenance (non-coherent per-XCD L2s), paid by 1134
// blocks. R4: back to R2's 3-kernel shape (no fence), KEEP the R3 channel
// split (box=5 loads/thread, cls=1 load/thread) that cuts serial load depth.
// Load depth is the controlling variable: reset()'s 268MB ws-poison fill
// thrashes the LLC between replays, so every scattered load pays ~0.9us HBM
// latency; R1's 54-deep chain = 50us, 5-deep ~ 1.5us.
// ---------------------------------------------------------------------------

#define NBLK_SWEEP 1050
#define NBLK_BOX 6     // 1536 threads: one per (target,scale), ch0..4
#define NBLK_CLS 78    // 19968 threads: one per (target,scale,class)
#define NBLK_TOTAL (NBLK_SWEEP + NBLK_BOX + NBLK_CLS)   // 1134

namespace {
__device__ __forceinline__ float bce_logits(float x, float t) {
    return fmaxf(x, 0.0f) - x * t + log1pf(expf(-fabsf(x)));
}
__device__ __forceinline__ float focal_term(float x, float t) {
    float b = bce_logits(x, t);
    float pt = expf(-b);
    float om = fmaxf(1.0f - pt, 0.0f);
    return 0.25f * om * sqrtf(om) * b;   // alpha=0.25, gamma=1.5
}
} // namespace

__global__ void fnl_zero_ws(float* __restrict__ ws) {
    if (threadIdx.x < 16) ws[threadIdx.x] = 0.0f;
}

__global__ void __launch_bounds__(256) fnl_main(
    const float* __restrict__ p0, const float* __restrict__ p1,
    const float* __restrict__ p2, const float* __restrict__ tg,
    float* __restrict__ ws) {
    __shared__ float sm[4];
    const float* const ps[3] = {p0, p1, p2};
    const int gss[3] = {160, 80, 40};

    if (blockIdx.x < NBLK_SWEEP) {
        // ---- focal(x,0) sweep over channel-4 planes (float4) --------------
        int i = blockIdx.x * 256 + threadIdx.x;
        const float* p;
        int hw4, scale, idx;
        if (i < 204800)      { p = p0; hw4 = 6400; scale = 0; idx = i; }
        else if (i < 256000) { p = p1; hw4 = 1600; scale = 1; idx = i - 204800; }
        else                 { p = p2; hw4 = 400;  scale = 2; idx = i - 256000; }
        int b = idx / hw4;
        int pos4 = idx - b * hw4;
        int hw = hw4 * 4;
        const float4* src =
            reinterpret_cast<const float4*>(p + (size_t)b * 18 * hw + (size_t)4 * hw);
        float4 x = src[pos4];
        float v = focal_term(x.x, 0.0f) + focal_term(x.y, 0.0f) +
                  focal_term(x.z, 0.0f) + focal_term(x.w, 0.0f);

        for (int off = 32; off; off >>= 1) v += __shfl_down(v, off);
        if ((threadIdx.x & 63) == 0) sm[threadIdx.x >> 6] = v;
        __syncthreads();
        if (threadIdx.x == 0)
            atomicAdd(&ws[scale * 4 + 0], sm[0] + sm[1] + sm[2] + sm[3]);
    } else if (blockIdx.x < NBLK_SWEEP + NBLK_BOX) {
        // ---- box + obj-correction: one thread per (target,scale) ----------
        int gid = (blockIdx.x - NBLK_SWEEP) * 256 + threadIdx.x;  // [0,1536)
        int s = gid >> 9;                            // wave-uniform
        int t = gid & 511;

        const float bi  = tg[t * 6 + 0];
        const float cx  = tg[t * 6 + 2];
        const float cy  = tg[t * 6 + 3];
        const float w   = tg[t * 6 + 4];
        const float h   = tg[t * 6 + 5];
        const int b = (int)bi;

        const int gs = gss[s];
        const float fgs = (float)gs;
        float cxs = cx * fgs, cys = cy * fgs;
        int gi = (int)floorf(cxs); gi = min(max(gi, 0), gs - 1);
        int gj = (int)floorf(cys); gj = min(max(gj, 0), gs - 1);
        const float tx = cxs - (float)gi;
        const float ty = cys - (float)gj;
        const float tw = w * fgs;
        const float th = h * fgs;

        const int hw = gs * gs;
        const float* base = ps[s] + (size_t)b * 18 * hw + (size_t)gj * gs + gi;
        // 5 independent loads — issue together, one ~0.9us latency round.
        float pr0 = base[0];
        float pr1 = base[(size_t)hw];
        float pr2 = base[(size_t)2 * hw];
        float pr3 = base[(size_t)3 * hw];
        float pr4 = base[(size_t)4 * hw];

        const float px = 1.0f / (1.0f + expf(-pr0));
        const float py = 1.0f / (1.0f + expf(-pr1));
        const float pw = pr2;
        const float ph = pr3;

        const float eps = 1e-7f;
        float px1 = px - pw * 0.5f, px2 = px + pw * 0.5f;
        float py1 = py - ph * 0.5f, py2 = py + ph * 0.5f;
        float tx1 = tx - tw * 0.5f, tx2 = tx + tw * 0.5f;
        float ty1 = ty - th * 0.5f, ty2 = ty + th * 0.5f;
        float iw = fmaxf(fminf(px2, tx2) - fmaxf(px1, tx1), 0.0f);
        float ih = fmaxf(fminf(py2, ty2) - fmaxf(py1, ty1), 0.0f);
        float inter = iw * ih;
        float uni = pw * ph + tw * th - inter + eps;
        float iou = inter / uni;
        float ew = fmaxf(fmaxf(px2, tx2) - fminf(px1, tx1), 0.0f);
        float eh = fmaxf(fmaxf(py2, ty2) - fminf(py1, ty1), 0.0f);
        float c2 = ew * ew + eh * eh + eps;
        float rho2 = (px - tx) * (px - tx) + (py - ty) * (py - ty);
        const float four_over_pi2 = 0.405284734569351085775517852f;
        float dat = atanf(tw / (th + eps)) - atanf(pw / (ph + eps));
        float v = four_over_pi2 * dat * dat;
        float alpha = v / (1.0f - iou + v + eps);
        float ciou = iou - (rho2 / c2 + v * alpha);

        float box = 1.0f - ciou;
        float tobj = fmaxf(ciou, 0.0f);
        float corr = focal_term(pr4, tobj) - focal_term(pr4, 0.0f);

        for (int off = 32; off; off >>= 1) {
            box  += __shfl_down(box, off);
            corr += __shfl_down(corr, off);
        }
        if ((threadIdx.x & 63) == 0) {
            atomicAdd(&ws[s * 4 + 1], box);
            atomicAdd(&ws[s * 4 + 3], corr);
        }
    } else {
        // ---- cls: one thread per (target,scale,class), 1 load each --------
        int g = (blockIdx.x - NBLK_SWEEP - NBLK_BOX) * 256 + threadIdx.x;
        int sk = g >> 9;          // wave-uniform: (s*13 + k)
        int t  = g & 511;
        int s  = sk / 13;
        int k  = sk - s * 13;

        const float bi  = tg[t * 6 + 0];
        const float clf = tg[t * 6 + 1];
        const float cx  = tg[t * 6 + 2];
        const float cy  = tg[t * 6 + 3];
        const int b = (int)bi;
        const int cls = (int)clf;

        const int gs = gss[s];
        const float fgs = (float)gs;
        int gi = (int)floorf(cx * fgs); gi = min(max(gi, 0), gs - 1);
        int gj = (int)floorf(cy * fgs); gj = min(max(gj, 0), gs - 1);

        const int hw = gs * gs;
        float x = ps[s][(size_t)b * 18 * hw + (size_t)(5 + k) * hw +
                        (size_t)gj * gs + gi];
        float tc = (k == cls) ? 0.95f : 0.0f;
        float c = bce_logits(x, tc);

        for (int off = 32; off; off >>= 1) c += __shfl_down(c, off);
        if ((threadIdx.x & 63) == 0) atomicAdd(&ws[s * 4 + 2], c);
    }
}

__global__ void fnl_finalize(const float* __restrict__ ws, float* __restrict__ out) {
    if (threadIdx.x != 0 || blockIdx.x != 0) return;
    const float cells[3] = {819200.0f, 204800.0f, 51200.0f};
    const float npos = 512.0f;
    float lb = 0.0f, lo = 0.0f, lc = 0.0f;
    for (int s = 0; s < 3; ++s) {
        lb += ws[s * 4 + 1] / npos;
        lo += (ws[s * 4 + 0] + ws[s * 4 + 3]) / cells[s];
        lc += ws[s * 4 + 2] / (npos * 13.0f);
    }
    out[0] = 5.0f * lb + 1.0f * lo + 0.5f * lc;
    out[1] = lb;
    out[2] = lo;
    out[3] = lc;
}

extern "C" void kernel_launch(void* const* d_in, const int* in_sizes, int n_in,
                              void* d_out, int out_size, void* d_ws, size_t ws_size,
                              hipStream_t stream) {
    const float* p0 = (const float*)d_in[0];
    const float* p1 = (const float*)d_in[1];
    const float* p2 = (const float*)d_in[2];
    const float* tg = (const float*)d_in[3];
    float* ws = (float*)d_ws;
    float* out = (float*)d_out;

    fnl_zero_ws<<<1, 64, 0, stream>>>(ws);
    fnl_main<<<NBLK_TOTAL, 256, 0, stream>>>(p0, p1, p2, tg, ws);
    fnl_finalize<<<1, 64, 0, stream>>>(ws, out);
}

// Round 5
// 17.199 us; speedup vs baseline: 2.4595x; 1.8700x over previous
//
#include <hip/hip_runtime.h>
#include <math.h>

// ---------------------------------------------------------------------------
// FashionNetLoss: 3-scale YOLO-ish loss.
//  * obj focal loss is a mean over ALL cells, but target is 0 except at the
//    512 occupied cells per scale -> sum focal(x,0) over all cells, then a
//    per-target correction focal(x,t)-focal(x,0).
//  * box & cls losses only involve the 512 occupied cells per scale.
//  * npos == 512 per scale.
//
// R4 post-mortem: channel-split changed nothing (32.9->32.2us) — the
// structure-invariant residual is ~1400 same-cacheline global atomicAdds
// from 1134 blocks across 8 non-coherent-L2 XCDs (~15-20ns serialized RMW
// each ~= 25us). R5: ZERO global atomics. Every block is (category,scale)-
// uniform, so it plain-stores its two reduced partials to a private slot
// ws[2*bid..2*bid+1]; a 1-block finalize reduces the 1134 slots (mapping
// reconstructed from block index). zero_ws kernel dropped (all slots written
// every call). 2 launches total.
//
// Block map: [0,800) sweep s0, [800,1000) sweep s1, [1000,1050) sweep s2,
//            [1050,1056) box (s=(i-1050)>>1), [1056,1134) cls (s=sk/13).
// Slot: {v0,v1} = sweep:{focal,0} box:{box,corr} cls:{clsum,0}.
// ---------------------------------------------------------------------------

#define NBLK_SWEEP 1050
#define NBLK_BOX 6     // 1536 threads: one per (target,scale), ch0..4
#define NBLK_CLS 78    // 19968 threads: one per (target,scale,class)
#define NBLK_TOTAL (NBLK_SWEEP + NBLK_BOX + NBLK_CLS)   // 1134

namespace {
__device__ __forceinline__ float bce_logits(float x, float t) {
    return fmaxf(x, 0.0f) - x * t + log1pf(expf(-fabsf(x)));
}
__device__ __forceinline__ float focal_term(float x, float t) {
    float b = bce_logits(x, t);
    float pt = expf(-b);
    float om = fmaxf(1.0f - pt, 0.0f);
    return 0.25f * om * sqrtf(om) * b;   // alpha=0.25, gamma=1.5
}
} // namespace

__global__ void __launch_bounds__(256) fnl_main(
    const float* __restrict__ p0, const float* __restrict__ p1,
    const float* __restrict__ p2, const float* __restrict__ tg,
    float* __restrict__ ws) {
    __shared__ float sm0[4], sm1[4];
    const float* const ps[3] = {p0, p1, p2};
    const int gss[3] = {160, 80, 40};

    float v0 = 0.0f, v1 = 0.0f;   // per-thread partials for this block's slot

    if (blockIdx.x < NBLK_SWEEP) {
        // ---- focal(x,0) sweep over channel-4 planes (float4) --------------
        int i = blockIdx.x * 256 + threadIdx.x;
        const float* p;
        int hw4, idx;
        if (i < 204800)      { p = p0; hw4 = 6400; idx = i; }
        else if (i < 256000) { p = p1; hw4 = 1600; idx = i - 204800; }
        else                 { p = p2; hw4 = 400;  idx = i - 256000; }
        int b = idx / hw4;
        int pos4 = idx - b * hw4;
        int hw = hw4 * 4;
        const float4* src =
            reinterpret_cast<const float4*>(p + (size_t)b * 18 * hw + (size_t)4 * hw);
        float4 x = src[pos4];
        v0 = focal_term(x.x, 0.0f) + focal_term(x.y, 0.0f) +
             focal_term(x.z, 0.0f) + focal_term(x.w, 0.0f);
    } else if (blockIdx.x < NBLK_SWEEP + NBLK_BOX) {
        // ---- box + obj-correction: one thread per (target,scale) ----------
        int gid = (blockIdx.x - NBLK_SWEEP) * 256 + threadIdx.x;  // [0,1536)
        int s = gid >> 9;                            // block-uniform
        int t = gid & 511;

        const float bi  = tg[t * 6 + 0];
        const float cx  = tg[t * 6 + 2];
        const float cy  = tg[t * 6 + 3];
        const float w   = tg[t * 6 + 4];
        const float h   = tg[t * 6 + 5];
        const int b = (int)bi;

        const int gs = gss[s];
        const float fgs = (float)gs;
        float cxs = cx * fgs, cys = cy * fgs;
        int gi = (int)floorf(cxs); gi = min(max(gi, 0), gs - 1);
        int gj = (int)floorf(cys); gj = min(max(gj, 0), gs - 1);
        const float tx = cxs - (float)gi;
        const float ty = cys - (float)gj;
        const float tw = w * fgs;
        const float th = h * fgs;

        const int hw = gs * gs;
        const float* base = ps[s] + (size_t)b * 18 * hw + (size_t)gj * gs + gi;
        // 5 independent loads — one latency round.
        float pr0 = base[0];
        float pr1 = base[(size_t)hw];
        float pr2 = base[(size_t)2 * hw];
        float pr3 = base[(size_t)3 * hw];
        float pr4 = base[(size_t)4 * hw];

        const float px = 1.0f / (1.0f + expf(-pr0));
        const float py = 1.0f / (1.0f + expf(-pr1));
        const float pw = pr2;
        const float ph = pr3;

        const float eps = 1e-7f;
        float px1 = px - pw * 0.5f, px2 = px + pw * 0.5f;
        float py1 = py - ph * 0.5f, py2 = py + ph * 0.5f;
        float tx1 = tx - tw * 0.5f, tx2 = tx + tw * 0.5f;
        float ty1 = ty - th * 0.5f, ty2 = ty + th * 0.5f;
        float iw = fmaxf(fminf(px2, tx2) - fmaxf(px1, tx1), 0.0f);
        float ih = fmaxf(fminf(py2, ty2) - fmaxf(py1, ty1), 0.0f);
        float inter = iw * ih;
        float uni = pw * ph + tw * th - inter + eps;
        float iou = inter / uni;
        float ew = fmaxf(fmaxf(px2, tx2) - fminf(px1, tx1), 0.0f);
        float eh = fmaxf(fmaxf(py2, ty2) - fminf(py1, ty1), 0.0f);
        float c2 = ew * ew + eh * eh + eps;
        float rho2 = (px - tx) * (px - tx) + (py - ty) * (py - ty);
        const float four_over_pi2 = 0.405284734569351085775517852f;
        float dat = atanf(tw / (th + eps)) - atanf(pw / (ph + eps));
        float v = four_over_pi2 * dat * dat;
        float alpha = v / (1.0f - iou + v + eps);
        float ciou = iou - (rho2 / c2 + v * alpha);

        v0 = 1.0f - ciou;                                     // box
        float tobj = fmaxf(ciou, 0.0f);
        v1 = focal_term(pr4, tobj) - focal_term(pr4, 0.0f);   // obj corr
    } else {
        // ---- cls: one thread per (target,scale,class), 1 load each --------
        int g = (blockIdx.x - NBLK_SWEEP - NBLK_BOX) * 256 + threadIdx.x;
        int sk = g >> 9;          // block-uniform: (s*13 + k)
        int t  = g & 511;
        int s  = sk / 13;
        int k  = sk - s * 13;

        const float bi  = tg[t * 6 + 0];
        const float clf = tg[t * 6 + 1];
        const float cx  = tg[t * 6 + 2];
        const float cy  = tg[t * 6 + 3];
        const int b = (int)bi;
        const int cls = (int)clf;

        const int gs = gss[s];
        const float fgs = (float)gs;
        int gi = (int)floorf(cx * fgs); gi = min(max(gi, 0), gs - 1);
        int gj = (int)floorf(cy * fgs); gj = min(max(gj, 0), gs - 1);

        const int hw = gs * gs;
        float x = ps[s][(size_t)b * 18 * hw + (size_t)(5 + k) * hw +
                        (size_t)gj * gs + gi];
        float tc = (k == cls) ? 0.95f : 0.0f;
        v0 = bce_logits(x, tc);
    }

    // ---- block reduce, plain store to private slot (NO global atomics) ----
    for (int off = 32; off; off >>= 1) {
        v0 += __shfl_down(v0, off);
        v1 += __shfl_down(v1, off);
    }
    if ((threadIdx.x & 63) == 0) {
        sm0[threadIdx.x >> 6] = v0;
        sm1[threadIdx.x >> 6] = v1;
    }
    __syncthreads();
    if (threadIdx.x == 0) {
        ws[2 * blockIdx.x + 0] = sm0[0] + sm0[1] + sm0[2] + sm0[3];
        ws[2 * blockIdx.x + 1] = sm1[0] + sm1[1] + sm1[2] + sm1[3];
    }
}

__global__ void __launch_bounds__(256) fnl_finalize(
    const float* __restrict__ ws, float* __restrict__ out) {
    // acc layout: [s*4 + {0:focal,1:box,2:cls,3:corr}]
    float a[12];
    #pragma unroll
    for (int j = 0; j < 12; ++j) a[j] = 0.0f;

    for (int i = threadIdx.x; i < NBLK_TOTAL; i += 256) {
        float v0 = ws[2 * i + 0];
        float v1 = ws[2 * i + 1];
        if (i < 800)            a[0 * 4 + 0] += v0;
        else if (i < 1000)      a[1 * 4 + 0] += v0;
        else if (i < NBLK_SWEEP) a[2 * 4 + 0] += v0;
        else if (i < NBLK_SWEEP + NBLK_BOX) {
            int s = (i - NBLK_SWEEP) >> 1;
            a[s * 4 + 1] += v0;
            a[s * 4 + 3] += v1;
        } else {
            int sk = ((i - NBLK_SWEEP - NBLK_BOX) * 256) >> 9;
            int s = sk / 13;
            a[s * 4 + 2] += v0;
        }
    }

    __shared__ float red[12];
    if (threadIdx.x < 12) red[threadIdx.x] = 0.0f;
    __syncthreads();
    #pragma unroll
    for (int j = 0; j < 12; ++j) {
        float v = a[j];
        for (int off = 32; off; off >>= 1) v += __shfl_down(v, off);
        if ((threadIdx.x & 63) == 0) atomicAdd(&red[j], v);   // LDS atomic
    }
    __syncthreads();

    if (threadIdx.x == 0) {
        const float cells[3] = {819200.0f, 204800.0f, 51200.0f};
        const float npos = 512.0f;
        float lb = 0.0f, lo = 0.0f, lc = 0.0f;
        for (int s = 0; s < 3; ++s) {
            lb += red[s * 4 + 1] / npos;
            lo += (red[s * 4 + 0] + red[s * 4 + 3]) / cells[s];
            lc += red[s * 4 + 2] / (npos * 13.0f);
        }
        out[0] = 5.0f * lb + 1.0f * lo + 0.5f * lc;
        out[1] = lb;
        out[2] = lo;
        out[3] = lc;
    }
}

extern "C" void kernel_launch(void* const* d_in, const int* in_sizes, int n_in,
                              void* d_out, int out_size, void* d_ws, size_t ws_size,
                              hipStream_t stream) {
    const float* p0 = (const float*)d_in[0];
    const float* p1 = (const float*)d_in[1];
    const float* p2 = (const float*)d_in[2];
    const float* tg = (const float*)d_in[3];
    float* ws = (float*)d_ws;
    float* out = (float*)d_out;

    fnl_main<<<NBLK_TOTAL, 256, 0, stream>>>(p0, p1, p2, tg, ws);
    fnl_finalize<<<1, 256, 0, stream>>>(ws, out);
}

// Round 6
// 14.771 us; speedup vs baseline: 2.8638x; 1.1644x over previous
//
#include <hip/hip_runtime.h>
#include <math.h>

// ---------------------------------------------------------------------------
// FashionNetLoss: 3-scale YOLO-ish loss.
//  * obj focal loss is a mean over ALL cells, but target is 0 except at the
//    512 occupied cells per scale -> sum focal(x,0) over all cells, then a
//    per-target correction focal(x,t)-focal(x,0).
//  * box & cls losses only involve the 512 occupied cells per scale.
//  * npos == 512 per scale.
//
// R5 post-mortem: removing all global atomics cut 32.2->17.2us (confirmed
// ~13ns per serialized same-line atomic across non-coherent XCD L2s).
// R6: (1) fast __expf/__logf softplus in sweep+cls (libm log1pf is ~50
// instrs; v_exp/v_log are 1 each) — absmax threshold 0.43 gives huge room,
// box path stays exact libm; (2) gather blocks FIRST so their scattered
// latency hides under the sweep; (3) 2 float4/thread sweep -> 525 blocks.
// Zero global atomics; block-private slots ws[2*bid..+1]; 2 launches.
//
// Block map: [0,6) box (s=gid>>9), [6,84) cls (sk=(bid-6)>>1, s=sk/13),
//            [84,609) sweep chunks: [0,400)=s0, [400,500)=s1, [500,525)=s2.
// Slot: {v0,v1} = box:{box,corr} cls:{clsum,0} sweep:{focal,0}.
// ---------------------------------------------------------------------------

#define NBLK_BOX 6     // 1536 threads: one per (target,scale), ch0..4
#define NBLK_CLS 78    // 19968 threads: one per (target,scale,class)
#define NBLK_TGT (NBLK_BOX + NBLK_CLS)            // 84
#define NBLK_SWEEP 525 // 512 float4 per block, 2 per thread
#define NBLK_TOTAL (NBLK_TGT + NBLK_SWEEP)        // 609

namespace {
// exact path (box blocks only)
__device__ __forceinline__ float bce_logits(float x, float t) {
    return fmaxf(x, 0.0f) - x * t + log1pf(expf(-fabsf(x)));
}
__device__ __forceinline__ float focal_term(float x, float t) {
    float b = bce_logits(x, t);
    float pt = expf(-b);
    float om = fmaxf(1.0f - pt, 0.0f);
    return 0.25f * om * sqrtf(om) * b;   // alpha=0.25, gamma=1.5
}
// fast path (sweep + cls): v_exp_f32 / v_log_f32 based
__device__ __forceinline__ float softplus_neg(float u) {  // log1p(exp(u)), u<=0
    return __logf(1.0f + __expf(u));
}
__device__ __forceinline__ float bce_fast(float x, float t) {
    return fmaxf(x, 0.0f) - x * t + softplus_neg(-fabsf(x));
}
__device__ __forceinline__ float focal0_fast(float x) {   // focal(x, 0)
    float b = fmaxf(x, 0.0f) + softplus_neg(-fabsf(x));
    float pt = __expf(-b);
    float om = fmaxf(1.0f - pt, 0.0f);
    return 0.25f * om * sqrtf(om) * b;
}
} // namespace

__global__ void __launch_bounds__(256) fnl_main(
    const float* __restrict__ p0, const float* __restrict__ p1,
    const float* __restrict__ p2, const float* __restrict__ tg,
    float* __restrict__ ws) {
    __shared__ float sm0[4], sm1[4];
    const float* const ps[3] = {p0, p1, p2};
    const int gss[3] = {160, 80, 40};

    float v0 = 0.0f, v1 = 0.0f;   // per-thread partials for this block's slot

    if (blockIdx.x < NBLK_BOX) {
        // ---- box + obj-correction: one thread per (target,scale) ----------
        int gid = blockIdx.x * 256 + threadIdx.x;    // [0,1536)
        int s = gid >> 9;                            // block-uniform
        int t = gid & 511;

        const float bi  = tg[t * 6 + 0];
        const float cx  = tg[t * 6 + 2];
        const float cy  = tg[t * 6 + 3];
        const float w   = tg[t * 6 + 4];
        const float h   = tg[t * 6 + 5];
        const int b = (int)bi;

        const int gs = gss[s];
        const float fgs = (float)gs;
        float cxs = cx * fgs, cys = cy * fgs;
        int gi = (int)floorf(cxs); gi = min(max(gi, 0), gs - 1);
        int gj = (int)floorf(cys); gj = min(max(gj, 0), gs - 1);
        const float tx = cxs - (float)gi;
        const float ty = cys - (float)gj;
        const float tw = w * fgs;
        const float th = h * fgs;

        const int hw = gs * gs;
        const float* base = ps[s] + (size_t)b * 18 * hw + (size_t)gj * gs + gi;
        // 5 independent loads — one latency round.
        float pr0 = base[0];
        float pr1 = base[(size_t)hw];
        float pr2 = base[(size_t)2 * hw];
        float pr3 = base[(size_t)3 * hw];
        float pr4 = base[(size_t)4 * hw];

        const float px = 1.0f / (1.0f + expf(-pr0));
        const float py = 1.0f / (1.0f + expf(-pr1));
        const float pw = pr2;
        const float ph = pr3;

        const float eps = 1e-7f;
        float px1 = px - pw * 0.5f, px2 = px + pw * 0.5f;
        float py1 = py - ph * 0.5f, py2 = py + ph * 0.5f;
        float tx1 = tx - tw * 0.5f, tx2 = tx + tw * 0.5f;
        float ty1 = ty - th * 0.5f, ty2 = ty + th * 0.5f;
        float iw = fmaxf(fminf(px2, tx2) - fmaxf(px1, tx1), 0.0f);
        float ih = fmaxf(fminf(py2, ty2) - fmaxf(py1, ty1), 0.0f);
        float inter = iw * ih;
        float uni = pw * ph + tw * th - inter + eps;
        float iou = inter / uni;
        float ew = fmaxf(fmaxf(px2, tx2) - fminf(px1, tx1), 0.0f);
        float eh = fmaxf(fmaxf(py2, ty2) - fminf(py1, ty1), 0.0f);
        float c2 = ew * ew + eh * eh + eps;
        float rho2 = (px - tx) * (px - tx) + (py - ty) * (py - ty);
        const float four_over_pi2 = 0.405284734569351085775517852f;
        float dat = atanf(tw / (th + eps)) - atanf(pw / (ph + eps));
        float v = four_over_pi2 * dat * dat;
        float alpha = v / (1.0f - iou + v + eps);
        float ciou = iou - (rho2 / c2 + v * alpha);

        v0 = 1.0f - ciou;                                     // box
        float tobj = fmaxf(ciou, 0.0f);
        v1 = focal_term(pr4, tobj) - focal_term(pr4, 0.0f);   // obj corr
    } else if (blockIdx.x < NBLK_TGT) {
        // ---- cls: one thread per (target,scale,class), 1 load each --------
        int g = (blockIdx.x - NBLK_BOX) * 256 + threadIdx.x;
        int sk = g >> 9;          // block-uniform: (s*13 + k)
        int t  = g & 511;
        int s  = sk / 13;
        int k  = sk - s * 13;

        const float bi  = tg[t * 6 + 0];
        const float clf = tg[t * 6 + 1];
        const float cx  = tg[t * 6 + 2];
        const float cy  = tg[t * 6 + 3];
        const int b = (int)bi;
        const int cls = (int)clf;

        const int gs = gss[s];
        const float fgs = (float)gs;
        int gi = (int)floorf(cx * fgs); gi = min(max(gi, 0), gs - 1);
        int gj = (int)floorf(cy * fgs); gj = min(max(gj, 0), gs - 1);

        const int hw = gs * gs;
        float x = ps[s][(size_t)b * 18 * hw + (size_t)(5 + k) * hw +
                        (size_t)gj * gs + gi];
        float tc = (k == cls) ? 0.95f : 0.0f;
        v0 = bce_fast(x, tc);
    } else {
        // ---- focal(x,0) sweep: 512 float4 per block, 2 per thread ---------
        int chunk = blockIdx.x - NBLK_TGT;           // [0,525)
        const float* p;
        int hw4, base4;                              // block-uniform
        if (chunk < 400)      { p = p0; hw4 = 6400; base4 = 0; }
        else if (chunk < 500) { p = p1; hw4 = 1600; base4 = 204800; }
        else                  { p = p2; hw4 = 400;  base4 = 256000; }

        int j0 = chunk * 512 + threadIdx.x - base4;  // float4 idx in scale
        #pragma unroll
        for (int r = 0; r < 2; ++r) {
            int idx = j0 + r * 256;
            int b = idx / hw4;
            int pos4 = idx - b * hw4;
            int hw = hw4 * 4;
            const float4* src = reinterpret_cast<const float4*>(
                p + (size_t)b * 18 * hw + (size_t)4 * hw);
            float4 x = src[pos4];
            v0 += focal0_fast(x.x) + focal0_fast(x.y) +
                  focal0_fast(x.z) + focal0_fast(x.w);
        }
    }

    // ---- block reduce, plain store to private slot (NO global atomics) ----
    for (int off = 32; off; off >>= 1) {
        v0 += __shfl_down(v0, off);
        v1 += __shfl_down(v1, off);
    }
    if ((threadIdx.x & 63) == 0) {
        sm0[threadIdx.x >> 6] = v0;
        sm1[threadIdx.x >> 6] = v1;
    }
    __syncthreads();
    if (threadIdx.x == 0) {
        ws[2 * blockIdx.x + 0] = sm0[0] + sm0[1] + sm0[2] + sm0[3];
        ws[2 * blockIdx.x + 1] = sm1[0] + sm1[1] + sm1[2] + sm1[3];
    }
}

__global__ void __launch_bounds__(256) fnl_finalize(
    const float* __restrict__ ws, float* __restrict__ out) {
    // acc layout: [s*4 + {0:focal,1:box,2:cls,3:corr}]
    float a[12];
    #pragma unroll
    for (int j = 0; j < 12; ++j) a[j] = 0.0f;

    for (int i = threadIdx.x; i < NBLK_TOTAL; i += 256) {
        float v0 = ws[2 * i + 0];
        float v1 = ws[2 * i + 1];
        if (i < NBLK_BOX) {
            int s = i >> 1;
            a[s * 4 + 1] += v0;
            a[s * 4 + 3] += v1;
        } else if (i < NBLK_TGT) {
            int sk = (i - NBLK_BOX) >> 1;
            int s = sk / 13;
            a[s * 4 + 2] += v0;
        } else {
            int chunk = i - NBLK_TGT;
            int s = (chunk < 400) ? 0 : ((chunk < 500) ? 1 : 2);
            a[s * 4 + 0] += v0;
        }
    }

    __shared__ float red[12];
    if (threadIdx.x < 12) red[threadIdx.x] = 0.0f;
    __syncthreads();
    #pragma unroll
    for (int j = 0; j < 12; ++j) {
        float v = a[j];
        for (int off = 32; off; off >>= 1) v += __shfl_down(v, off);
        if ((threadIdx.x & 63) == 0) atomicAdd(&red[j], v);   // LDS atomic
    }
    __syncthreads();

    if (threadIdx.x == 0) {
        const float cells[3] = {819200.0f, 204800.0f, 51200.0f};
        const float npos = 512.0f;
        float lb = 0.0f, lo = 0.0f, lc = 0.0f;
        for (int s = 0; s < 3; ++s) {
            lb += red[s * 4 + 1] / npos;
            lo += (red[s * 4 + 0] + red[s * 4 + 3]) / cells[s];
            lc += red[s * 4 + 2] / (npos * 13.0f);
        }
        out[0] = 5.0f * lb + 1.0f * lo + 0.5f * lc;
        out[1] = lb;
        out[2] = lo;
        out[3] = lc;
    }
}

extern "C" void kernel_launch(void* const* d_in, const int* in_sizes, int n_in,
                              void* d_out, int out_size, void* d_ws, size_t ws_size,
                              hipStream_t stream) {
    const float* p0 = (const float*)d_in[0];
    const float* p1 = (const float*)d_in[1];
    const float* p2 = (const float*)d_in[2];
    const float* tg = (const float*)d_in[3];
    float* ws = (float*)d_ws;
    float* out = (float*)d_out;

    fnl_main<<<NBLK_TOTAL, 256, 0, stream>>>(p0, p1, p2, tg, ws);
    fnl_finalize<<<1, 256, 0, stream>>>(ws, out);
}